// Round 12
// baseline (1779.069 us; speedup 1.0000x reference)
//
#include <hip/hip_runtime.h>
#include <hip/hip_bf16.h>
#include <stdint.h>

#define DEPTH 4
#define DIM   1024
#define DH    4096
#define NH    8
#define DQ    128
#define VOC   32000
#define BATCH 2
#define SEQ   1024
#define ROWS  (BATCH*SEQ)   // 2048
#define CROSSK 256          // merged cross K-prefix in PV
#define LDS_X (CROSSK + SEQ)  // 1280: row length of SbX / vte

#define PQKV  ((long long)ROWS*DIM)
#define PQKV3 ((long long)ROWS*3*DIM)
#define PROT  ((long long)BATCH*NH*SEQ*2*DQ)
#define PMID  ((long long)ROWS*DH)
#define PY    ((long long)ROWS*DIM)

typedef __hip_bfloat16 bf16;
using f32x4  = __attribute__((ext_vector_type(4))) float;
using bf16x8 = __attribute__((ext_vector_type(8))) __bf16;

__device__ __forceinline__ unsigned short bcu(bf16 h) {
  return __builtin_bit_cast(unsigned short, h);
}

__device__ __forceinline__ void wpair(bf16* p, long long off, long long plane, float v) {
  bf16 hi = __float2bfloat16(v);
  p[off] = hi;
  p[off + plane] = __float2bfloat16(v - __bfloat162float(hi));
}

__device__ __forceinline__ void gload_lds16(const void* g, void* l) {
  __builtin_amdgcn_global_load_lds(
      (const __attribute__((address_space(1))) void*)g,
      (__attribute__((address_space(3))) void*)(uintptr_t)l,
      16, 0, 0);
}

#define VMW(n) asm volatile("s_waitcnt vmcnt(" #n ")" ::: "memory")

// XCD-aware bijective remap — validated for the 256^2 tile (r8: FETCH 529->222MB)
__device__ __forceinline__ int2 xcd_remap(int gx, int gy) {
  int f   = blockIdx.x + gx * blockIdx.y;
  int nwg = gx * gy;
  int fp  = (f & 7) * (nwg >> 3) + (f >> 3);
  return int2{fp % gx, fp / gx};
}

// ===========================================================================
// 256x256 8-phase counted-vmcnt GEMM (tout only). C = A*B^T (+ Al*Bh pass).
// 512 thr (8 waves 2Mx4N), per-wave C 128x64, 128 KiB LDS dbuf.
// Per K-tile (BK=64): 4 quadrant phases q=0..3; B-frags -> regs at q0
// (B LDS region dead after q0 lgkm -> restageable mid-tile).
// Stage units/tile: [Bh0,Bh1,Ah0,Ah1], each = 2x global_load_lds (8KB).
// In-loop stages: q0:(j+1)Ah0  q1:(j+1)Ah1  q2:(j+2)Bh0  q3:(j+2)Bh1.
// Waits (in-order vmcnt retirement): after q1: vmcnt(8) -> (j)Ah1b resident
// for q2/q3 rows 192-255; after q3: vmcnt(5) -> (j+1){B,Ah0,Ah1a} resident.
// Tails: q1 VMW(0) on last tile; q3 VMW(1) on tile nt-2.
// ===========================================================================
template<int NPASS>
__global__ __launch_bounds__(512, 2)
void gemm256(const bf16* __restrict__ A, long long aoff1, int lda,
             const bf16* __restrict__ B, long long boff1, int ldb,
             float* __restrict__ C, int ldc,
             const float* __restrict__ bias,
             int M, int N, int K)
{
  __shared__ char sh[131072];
  const int tid  = threadIdx.x;
  const int lane = tid & 63;
  const int wid  = tid >> 6;
  const int wr   = wid >> 2;          // 0..1
  const int wc   = wid & 3;           // 0..3
  const int2 xy  = xcd_remap(gridDim.x, gridDim.y);
  const int tm   = xy.x * 256;
  const int tn   = xy.y * 256;
  const int nt   = K * NPASS / 64;

  // stage unit u of K-tile g (u: 0=Bh0 1=Bh1 2=Ah0 3=Ah1), 2 loads in order
  auto stage = [&](int g, int u) {
    const int b = g & 1;
    int kt = g * 64;
    long long ao = 0, bo = 0;
    if (NPASS == 2 && kt >= K) { ao = aoff1; bo = boff1; kt -= K; }
    const int isB  = (u < 2);
    const int half = u & 1;
#pragma unroll
    for (int ld = 0; ld < 2; ++ld) {
      int row = half*128 + ld*64 + (tid >> 3);
      int gc  = (tid & 7) ^ (row & 7);
      const bf16* src = isB
          ? (B + bo + (long long)(tn + row) * ldb + kt + gc*8)
          : (A + ao + (long long)(tm + row) * lda + kt + gc*8);
      gload_lds16(src, sh + b*65536 + (isB ? 32768 : 0) + half*16384
                        + ld*8192 + wid*1024);
    }
  };
  auto rdA = [&](int b, int mf, int ks) -> int4 {
    int m = wr*128 + mf*16 + (lane & 15);
    int c = ks*4 + (lane >> 4);
    return *(const int4*)(sh + b*65536 + m*128 + ((c ^ (m & 7)) << 4));
  };
  auto rdB = [&](int b, int g, int ks) -> int4 {
    int n = wc*64 + g*16 + (lane & 15);
    int c = ks*4 + (lane >> 4);
    return *(const int4*)(sh + b*65536 + 32768 + n*128 + ((c ^ (n & 7)) << 4));
  };

  f32x4 acc[8][4] = {};
  int4  bfr[2][4];

  // prologue: tile0 all units, tile1 B units; tile0 must be fully resident.
  stage(0,0); stage(0,1); stage(0,2); stage(0,3);
  if (nt > 1) { stage(1,0); stage(1,1); VMW(4); } else { VMW(0); }
  __builtin_amdgcn_s_barrier();
  __builtin_amdgcn_sched_barrier(0);

  for (int j = 0; j < nt; ++j) {
    const int b = j & 1;
#pragma unroll
    for (int q = 0; q < 4; ++q) {
      const int mf0 = 2*q, mf1 = 2*q + 1;
      int4 a0 = rdA(b, mf0, 0), a1 = rdA(b, mf0, 1);
      int4 a2 = rdA(b, mf1, 0), a3 = rdA(b, mf1, 1);
      if (q == 0) {
#pragma unroll
        for (int ks = 0; ks < 2; ++ks)
#pragma unroll
          for (int g = 0; g < 4; ++g) bfr[ks][g] = rdB(b, g, ks);
      }
      if (q == 0 && j+1 < nt) stage(j+1, 2);
      if (q == 1 && j+1 < nt) stage(j+1, 3);
      if (q == 2 && j+2 < nt) stage(j+2, 0);
      if (q == 3 && j+2 < nt) stage(j+2, 1);
      __builtin_amdgcn_s_barrier();
      asm volatile("s_waitcnt lgkmcnt(0)" ::: "memory");
      __builtin_amdgcn_sched_barrier(0);
      __builtin_amdgcn_s_setprio(1);
#pragma unroll
      for (int g = 0; g < 4; ++g)
        acc[mf0][g] = __builtin_amdgcn_mfma_f32_16x16x32_bf16(
            __builtin_bit_cast(bf16x8, a0), __builtin_bit_cast(bf16x8, bfr[0][g]),
            acc[mf0][g], 0, 0, 0);
#pragma unroll
      for (int g = 0; g < 4; ++g)
        acc[mf0][g] = __builtin_amdgcn_mfma_f32_16x16x32_bf16(
            __builtin_bit_cast(bf16x8, a1), __builtin_bit_cast(bf16x8, bfr[1][g]),
            acc[mf0][g], 0, 0, 0);
#pragma unroll
      for (int g = 0; g < 4; ++g)
        acc[mf1][g] = __builtin_amdgcn_mfma_f32_16x16x32_bf16(
            __builtin_bit_cast(bf16x8, a2), __builtin_bit_cast(bf16x8, bfr[0][g]),
            acc[mf1][g], 0, 0, 0);
#pragma unroll
      for (int g = 0; g < 4; ++g)
        acc[mf1][g] = __builtin_amdgcn_mfma_f32_16x16x32_bf16(
            __builtin_bit_cast(bf16x8, a3), __builtin_bit_cast(bf16x8, bfr[1][g]),
            acc[mf1][g], 0, 0, 0);
      __builtin_amdgcn_s_setprio(0);
      if (q == 1) { if (j+1 < nt) VMW(8); else VMW(0); }
      if (q == 3) { if (j+2 < nt) VMW(5); else if (j+1 < nt) VMW(1); }
      __builtin_amdgcn_s_barrier();
      __builtin_amdgcn_sched_barrier(0);
    }
  }

  const int col = lane & 15;
  const int rb  = (lane >> 4) << 2;
#pragma unroll
  for (int mf = 0; mf < 8; ++mf)
#pragma unroll
    for (int g = 0; g < 4; ++g) {
      long long gn = tn + wc*64 + g*16 + col;
      float bv = bias ? bias[gn] : 0.f;
#pragma unroll
      for (int r = 0; r < 4; ++r) {
        long long gm = tm + wr*128 + mf*16 + rb + r;
        C[gm * (long long)ldc + gn] = acc[mf][g][r] + bv;
      }
    }
}

// ---------------------------------------------------------------------------
// 128x128 2-phase batched GEMM (everything else; proven)
// ---------------------------------------------------------------------------
#define BM 128
#define BN 128
#define BKK 64
#define PL 16384

template<int EPI, int SA, int SB>
__global__ __launch_bounds__(256, (SA || SB) ? 2 : 4)
void gemm_bt(const bf16* __restrict__ A, long long sA, long long pA, int lda,
             const bf16* __restrict__ B, long long sB, long long pB, int ldb, int bmod,
             void* __restrict__ Cv, long long sC, long long pC, int ldc,
             const float* __restrict__ bias, int hmod,
             int M, int N, int K, int ksplit, int causal)
{
  __shared__ int4 sbuf[1024 * (2 + SA + SB)];
  char* Asb = (char*)sbuf;
  char* Bsb = Asb + PL * (1 + SA);

  const int tid  = threadIdx.x;
  const int lane = tid & 63;
  const int wave = tid >> 6;
  const int wr   = wave >> 1;
  const int wc   = wave & 1;
  const int z    = blockIdx.z;
  const int zb   = z / ksplit;
  const int ks   = z - zb * ksplit;
  const int Kc   = K / ksplit;
  const int k0   = ks * Kc;
  const int tm   = blockIdx.x * BM;
  const int tn   = blockIdx.y * BN;

  if (causal == 1 && tn >= tm + BM) return;
  int kend = k0 + Kc;
  if (causal == 2) {
    kend = min(kend, tm + BM + CROSSK);
    if (kend <= k0) return;
  }

  const bf16* Ab = A + (long long)zb * sA;
  const bf16* Bb = B + (long long)(zb % bmod) * sB;

  f32x4 acc[4][4] = {};

  for (int kt = k0; kt < kend; kt += BKK) {
#pragma unroll
    for (int j = 0; j < 4; ++j) {
      int slot0 = j*256 + wave*64;
      int i = slot0 + lane;
      int row = i >> 3;
      int gc  = (i & 7) ^ (row & 7);
      long long ga = (long long)(tm + row) * lda + kt + gc*8;
      long long gb = (long long)(tn + row) * ldb + kt + gc*8;
      gload_lds16(Ab + ga, Asb + slot0*16);
      if (SA) gload_lds16(Ab + pA + ga, Asb + PL + slot0*16);
      gload_lds16(Bb + gb, Bsb + slot0*16);
      if (SB) gload_lds16(Bb + pB + gb, Bsb + PL + slot0*16);
    }
    __syncthreads();
#pragma unroll
    for (int kh = 0; kh < 2; ++kh) {
      const int cb = kh*4 + (lane >> 4);
      int4 avh[4], bvh[4], avl[4], bvl[4];
#pragma unroll
      for (int mi = 0; mi < 4; ++mi) {
        int m = wr*64 + mi*16 + (lane & 15);
        int off = m*128 + ((cb ^ (m & 7)) << 4);
        avh[mi] = *(const int4*)(Asb + off);
        if (SA) avl[mi] = *(const int4*)(Asb + PL + off);
      }
#pragma unroll
      for (int nj = 0; nj < 4; ++nj) {
        int n = wc*64 + nj*16 + (lane & 15);
        int off = n*128 + ((cb ^ (n & 7)) << 4);
        bvh[nj] = *(const int4*)(Bsb + off);
        if (SB) bvl[nj] = *(const int4*)(Bsb + PL + off);
      }
#pragma unroll
      for (int mi = 0; mi < 4; ++mi)
#pragma unroll
        for (int nj = 0; nj < 4; ++nj)
          acc[mi][nj] = __builtin_amdgcn_mfma_f32_16x16x32_bf16(
              __builtin_bit_cast(bf16x8, avh[mi]),
              __builtin_bit_cast(bf16x8, bvh[nj]), acc[mi][nj], 0, 0, 0);
      if (SA)
#pragma unroll
        for (int mi = 0; mi < 4; ++mi)
#pragma unroll
          for (int nj = 0; nj < 4; ++nj)
            acc[mi][nj] = __builtin_amdgcn_mfma_f32_16x16x32_bf16(
                __builtin_bit_cast(bf16x8, avl[mi]),
                __builtin_bit_cast(bf16x8, bvh[nj]), acc[mi][nj], 0, 0, 0);
      if (SB)
#pragma unroll
        for (int mi = 0; mi < 4; ++mi)
#pragma unroll
          for (int nj = 0; nj < 4; ++nj)
            acc[mi][nj] = __builtin_amdgcn_mfma_f32_16x16x32_bf16(
                __builtin_bit_cast(bf16x8, avh[mi]),
                __builtin_bit_cast(bf16x8, bvl[nj]), acc[mi][nj], 0, 0, 0);
    }
    __syncthreads();
  }

  const float* dtab = (EPI == 7) ? bias + (zb % hmod) * (SEQ + 1) : nullptr;
  const int col = lane & 15;
  const int rb  = (lane >> 4) << 2;
  float* Cf = (float*)Cv + (long long)zb * sC;
  bf16*  Ch = (bf16*) Cv + (long long)zb * sC;

#pragma unroll
  for (int mi = 0; mi < 4; ++mi)
#pragma unroll
    for (int nj = 0; nj < 4; ++nj) {
      long long gn = tn + wc*64 + nj*16 + col;
      float bv_ = (EPI != 7 && bias && ks == 0) ? bias[gn] : 0.f;
#pragma unroll
      for (int r = 0; r < 4; ++r) {
        long long gm = tm + wr*64 + mi*16 + rb + r;
        float v = acc[mi][nj][r] + bv_;
        long long off = gm * (long long)ldc + gn;
        if (EPI == 0)      Cf[off] = v;
        else if (EPI == 3) { if (ksplit > 1) atomicAdd(&Cf[off], v); else Cf[off] += v; }
        else if (EPI == 5) wpair(Ch, off, pC, v);
        else if (EPI == 6) wpair(Ch, off, pC, v / (1.f + __expf(-v)));
        else {
          long long dlt = gm - gn;
          float dcy = (dlt >= 0) ? dtab[dlt] : 0.f;
          Ch[off] = __float2bfloat16(acc[mi][nj][r] * dcy);
        }
      }
    }
}

// ---------------------------------------------------------------------------
#define MC_LC (NH*DQ*DQ)
#define MC_TH (MC_LC + NH*DQ)
#define MC_B3 (MC_TH + 3*DIM)
#define MC_DC (MC_B3 + NH*(SEQ+1))
#define MC_ZR (MC_DC + (BATCH*NH*SEQ*DQ)/4)
__global__ void prep_kernel(const float* __restrict__ wq, const float* __restrict__ wk,
                            const float* __restrict__ wv, const float* __restrict__ wo,
                            const float* __restrict__ f1, const float* __restrict__ f2,
                            bf16* __restrict__ Wqkv, bf16* __restrict__ Wol,
                            bf16* __restrict__ Wf1, bf16* __restrict__ Wf2,
                            const float* __restrict__ lcr, const float* __restrict__ lci,
                            bf16* __restrict__ vte,
                            const float* __restrict__ pre, const float* __restrict__ pim,
                            float* __restrict__ theta,
                            const float* __restrict__ bq, const float* __restrict__ bk,
                            const float* __restrict__ bv, float* __restrict__ qkvbi,
                            const float* __restrict__ amp, float* __restrict__ dtab,
                            float4* __restrict__ retz) {
  const long long S1 = (long long)DIM*DIM;
  const long long S4 = S1 >> 2;
  const long long WPq = 3*S1;
  const long long CW4 = 12*S4;
  long long i = (long long)blockIdx.x * blockDim.x + threadIdx.x;
  if (i < CW4) {
    const float* src; bf16 *hi, *lo; long long j4;
    if (i < 3*S4) {
      int t = (int)(i / S4);
      src = (t == 0) ? wq : (t == 1) ? wk : wv;
      j4 = i - (long long)t * S4;
      hi = Wqkv + (long long)t * S1; lo = hi + WPq;
    } else if (i < 4*S4)  { src = wo; j4 = i - 3*S4; hi = Wol; lo = Wol + S1; }
    else if (i < 8*S4)    { src = f1; j4 = i - 4*S4; hi = Wf1; lo = Wf1 + 4*S1; }
    else                  { src = f2; j4 = i - 8*S4; hi = Wf2; lo = nullptr; }
    float4 v = ((const float4*)src)[j4];
    bf16 h0 = __float2bfloat16(v.x), h1 = __float2bfloat16(v.y);
    bf16 h2 = __float2bfloat16(v.z), h3 = __float2bfloat16(v.w);
    ((ushort4*)hi)[j4] = ushort4{bcu(h0), bcu(h1), bcu(h2), bcu(h3)};
    if (lo) {
      bf16 l0 = __float2bfloat16(v.x - __bfloat162float(h0));
      bf16 l1 = __float2bfloat16(v.y - __bfloat162float(h1));
      bf16 l2 = __float2bfloat16(v.z - __bfloat162float(h2));
      bf16 l3 = __float2bfloat16(v.w - __bfloat162float(h3));
      ((ushort4*)lo)[j4] = ushort4{bcu(l0), bcu(l1), bcu(l2), bcu(l3)};
    }
    return;
  }
  long long j = i - CW4;
  if (j < MC_LC) {
    int d = (int)(j & 127), e = (int)((j >> 7) & 127), h = (int)(j >> 14);
    float vr = lcr[((long long)h*DQ + d)*DQ + e];
    float vi = lci[((long long)h*DQ + d)*DQ + e];
    bf16 br = __float2bfloat16(vr), bi = __float2bfloat16(-vi);
#pragma unroll
    for (int b = 0; b < BATCH; ++b) {
      long long base = ((long long)(b*NH + h)*DQ + e) * LDS_X;
      vte[base + d]      = br;
      vte[base + DQ + d] = bi;
    }
  } else if (j < MC_TH) {
    int t = (int)(j - MC_LC);
    theta[t] = atan2f(pim[t], pre[t]);
  } else if (j < MC_B3) {
    int t = (int)(j - MC_TH);
    qkvbi[t] = (t < DIM) ? bq[t] : (t < 2*DIM) ? bk[t - DIM] : bv[t - 2*DIM];
  } else if (j < MC_DC) {
    int t = (int)(j - MC_B3);
    int h = t / (SEQ+1), n = t % (SEQ+1);
    float a = 1.f / (1.f + __expf(-amp[h]));
    dtab[t] = powf(a, (float)n);
  } else if (j < MC_ZR) {
    retz[j - MC_DC] = float4{0.f, 0.f, 0.f, 0.f};
  }
}

#define TIN_X4 ((long long)ROWS*VOC/4)
#define TIN_W4 (TIN_X4 + (long long)DIM*VOC/4)
#define TIN_H4 (TIN_W4 + (long long)ROWS*DIM/4)
__global__ void tinprep_kernel(const float* __restrict__ x, bf16* __restrict__ xb,
                               const float* __restrict__ tw, bf16* __restrict__ twb,
                               float4* __restrict__ hz) {
  long long i = (long long)blockIdx.x * blockDim.x + threadIdx.x;
  const float* src; bf16* dst; long long j;
  if (i < TIN_X4)      { src = x;  dst = xb;  j = i; }
  else if (i < TIN_W4) { src = tw; dst = twb; j = i - TIN_X4; }
  else if (i < TIN_H4) { hz[i - TIN_W4] = float4{0.f,0.f,0.f,0.f}; return; }
  else return;
  float4 v = ((const float4*)src)[j];
  ushort4 o{bcu(__float2bfloat16(v.x)), bcu(__float2bfloat16(v.y)),
            bcu(__float2bfloat16(v.z)), bcu(__float2bfloat16(v.w))};
  ((ushort4*)dst)[j] = o;
}

#define TAIL_H (PQKV)
#define TAIL_W (TAIL_H + (long long)VOC*DIM/4)
__global__ void tailprep_kernel(const float* __restrict__ h, bf16* __restrict__ hb,
                                const float* __restrict__ tw, bf16* __restrict__ twb) {
  long long i = (long long)blockIdx.x * blockDim.x + threadIdx.x;
  if (i < TAIL_H) {
    float v = h[i];
    bf16 hi = __float2bfloat16(v);
    hb[i] = hi;
    hb[i + PQKV] = __float2bfloat16(v - __bfloat162float(hi));
  } else if (i < TAIL_W) {
    long long j = i - TAIL_H;
    float4 v = ((const float4*)tw)[j];
    ushort4 o{bcu(__float2bfloat16(v.x)), bcu(__float2bfloat16(v.y)),
              bcu(__float2bfloat16(v.z)), bcu(__float2bfloat16(v.w))};
    ((ushort4*)twb)[j] = o;
  }
}

__global__ void ln_kernel(const float* __restrict__ in, bf16* __restrict__ out) {
  const int row = blockIdx.x;
  const int tid = threadIdx.x;          // 256
  const float4 v = ((const float4*)(in + (size_t)row*DIM))[tid];
  float s  = v.x + v.y + v.z + v.w;
  float s2 = v.x*v.x + v.y*v.y + v.z*v.z + v.w*v.w;
#pragma unroll
  for (int o = 32; o > 0; o >>= 1) { s += __shfl_xor(s, o); s2 += __shfl_xor(s2, o); }
  __shared__ float red[8];
  const int wv = tid >> 6;
  if ((tid & 63) == 0) { red[wv] = s; red[4 + wv] = s2; }
  __syncthreads();
  s  = red[0] + red[1] + red[2] + red[3];
  s2 = red[4] + red[5] + red[6] + red[7];
  const float mean = s * (1.f / DIM);
  const float var  = s2 * (1.f / DIM) - mean * mean;
  const float inv  = rsqrtf(var + 1e-5f);
  float e0 = (v.x - mean) * inv, e1 = (v.y - mean) * inv;
  float e2 = (v.z - mean) * inv, e3 = (v.w - mean) * inv;
  bf16 h0 = __float2bfloat16(e0), h1 = __float2bfloat16(e1);
  bf16 h2 = __float2bfloat16(e2), h3 = __float2bfloat16(e3);
  bf16 l0 = __float2bfloat16(e0 - __bfloat162float(h0));
  bf16 l1 = __float2bfloat16(e1 - __bfloat162float(h1));
  bf16 l2 = __float2bfloat16(e2 - __bfloat162float(h2));
  bf16 l3 = __float2bfloat16(e3 - __bfloat162float(h3));
  ((ushort4*)(out + (size_t)row*DIM))[tid]        = ushort4{bcu(h0), bcu(h1), bcu(h2), bcu(h3)};
  ((ushort4*)(out + PQKV + (size_t)row*DIM))[tid] = ushort4{bcu(l0), bcu(l1), bcu(l2), bcu(l3)};
}

__global__ void rotate_kernel(const bf16* __restrict__ qkv,
                              const float* __restrict__ theta_t,
                              const float* __restrict__ dtab,
                              bf16* __restrict__ qrot, bf16* __restrict__ krot,
                              bf16* __restrict__ SbX) {
  const int d = threadIdx.x, l = blockIdx.x, h = blockIdx.y, b = blockIdx.z;
  const float theta = theta_t[h*DQ + d];
  const long long rowb = (long long)(b*SEQ + l)*(3*DIM) + h*DQ + d;
  const float qv = __bfloat162float(qkv[rowb]) + __bfloat162float(qkv[rowb + PQKV3]);
  const float kv = __bfloat162float(qkv[rowb + DIM]) + __bfloat162float(qkv[rowb + DIM + PQKV3]);
  float sn, cs;
  sincosf(theta * (float)l, &sn, &cs);
  const long long dst = ((long long)(b*NH + h)*SEQ + l)*(2*DQ) + d;
  qrot[dst]      = __float2bfloat16(qv * cs);
  qrot[dst + DQ] = __float2bfloat16(qv * sn);
  krot[dst]      = __float2bfloat16(kv * cs);
  krot[dst + DQ] = __float2bfloat16(kv * sn);
  float sn2, cs2;
  sincosf(theta * (float)(l + 1), &sn2, &cs2);
  const float ad = dtab[h*(SEQ+1) + l + 1];
  const long long qw = ((long long)(b*NH + h)*SEQ + l)*LDS_X + d;
  SbX[qw]      = __float2bfloat16(qv * ad * cs2);
  SbX[qw + DQ] = __float2bfloat16(qv * ad * sn2);
}

__global__ void vt_kernel(const bf16* __restrict__ qkv, bf16* __restrict__ vte) {
  __shared__ float tile[64][65];
  const int t  = threadIdx.x;           // 256
  const int c  = t & 63, r4 = t >> 6;
  const int m0 = blockIdx.x * 64;
  const int d0 = blockIdx.y * 64;
  const int h  = blockIdx.z & (NH - 1);
  const int b  = blockIdx.z >> 3;
#pragma unroll
  for (int rr = 0; rr < 64; rr += 4) {
    const int m = m0 + rr + r4;
    const long long src = (long long)(b*SEQ + m)*(3*DIM) + 2*DIM + h*DQ + d0 + c;
    tile[rr + r4][c] = __bfloat162float(qkv[src]) + __bfloat162float(qkv[src + PQKV3]);
  }
  __syncthreads();
#pragma unroll
  for (int rr = 0; rr < 64; rr += 4) {
    const int d = rr + r4;
    vte[((long long)(b*NH + h)*DQ + d0 + d)*LDS_X + CROSSK + m0 + c] =
        __float2bfloat16(tile[c][d]);
  }
}

__global__ void siluret_kernel(const float* __restrict__ ret, bf16* __restrict__ y) {
  const int d = threadIdx.x, l = blockIdx.x, h = blockIdx.y, b = blockIdx.z;
  float r = ret[((long long)(b*NH + h)*SEQ + l)*DQ + d];
  float s = r / (1.f + __expf(-r));
  wpair(y, ((long long)(b*SEQ + l)*NH + h)*DQ + d, PY, s);
}

// ---------------------------------------------------------------------------
extern "C" void kernel_launch(void* const* d_in, const int* in_sizes, int n_in,
                              void* d_out, int out_size, void* d_ws, size_t ws_size,
                              hipStream_t stream) {
  const float* x      = (const float*)d_in[0];
  const float* tin_w  = (const float*)d_in[1];
  const float* tin_b  = (const float*)d_in[2];
  const float* tout_w = (const float*)d_in[3];
  const float* tout_b = (const float*)d_in[4];
  const float* wq_w   = (const float*)d_in[5];
  const float* wq_b   = (const float*)d_in[6];
  const float* wk_w   = (const float*)d_in[7];
  const float* wk_b   = (const float*)d_in[8];
  const float* wv_w   = (const float*)d_in[9];
  const float* wv_b   = (const float*)d_in[10];
  const float* wo_w   = (const float*)d_in[11];
  const float* wo_b   = (const float*)d_in[12];
  const float* f1_w   = (const float*)d_in[13];
  const float* f1_b   = (const float*)d_in[14];
  const float* f2_w   = (const float*)d_in[15];
  const float* f2_b   = (const float*)d_in[16];
  const float* phz_re = (const float*)d_in[17];
  const float* phz_im = (const float*)d_in[18];
  const float* amp    = (const float*)d_in[19];
  const float* lc_re  = (const float*)d_in[20];
  const float* lc_im  = (const float*)d_in[21];
  (void)in_sizes; (void)n_in; (void)out_size; (void)ws_size;

  char* w = (char*)d_ws;
  auto alloc = [&](size_t bytes) {
    char* p = w; w += (bytes + 255) & ~(size_t)255; return p;
  };
  auto palloc = [&](long long elems) {
    return (bf16*)alloc((size_t)elems * 2 * 2);
  };

  const long long WP = 3LL*DIM*DIM;
  float* h     = (float*)alloc((size_t)ROWS*DIM*4);
  float* ret   = (float*)alloc((size_t)BATCH*NH*SEQ*DQ*4);
  float* qkvbi = (float*)alloc((size_t)3*DIM*4);
  float* dtab  = (float*)alloc((size_t)NH*(SEQ+1)*4);
  float* theta = (float*)alloc((size_t)NH*DQ*4);
  bf16*  hb    = palloc(PQKV);
  bf16*  Wqkv  = palloc(WP);
  bf16*  Wol   = palloc((long long)DIM*DIM);
  bf16*  Wf1l  = palloc((long long)DH*DIM);
  bf16*  Wf2l  = (bf16*)alloc((size_t)DIM*DH*2);
  bf16*  qkvb  = palloc(PQKV3);
  bf16*  Wbig  = (bf16*)alloc((size_t)DIM*VOC*2);
  bf16*  qrot  = (bf16*)alloc((size_t)PROT*2);
  bf16*  krot  = (bf16*)alloc((size_t)PROT*2);
  bf16*  SbX   = (bf16*)alloc((size_t)BATCH*NH*SEQ*LDS_X*2);  // [qwb | S]
  bf16*  vte   = (bf16*)alloc((size_t)BATCH*NH*DQ*LDS_X*2);   // [lcc | V^T]
  bf16*  mid   = palloc(PMID);
  bf16*  xb = (bf16*)d_out;
  bf16*  yb = qkvb;

  auto gemm = [&](int epi, int sa, int sb, const bf16* A, long long sA, long long pA, int lda,
                  const bf16* B, long long sB, long long pB, int ldb, int bmod,
                  void* C, long long sC, long long pC, int ldc,
                  const float* bias, int hmod, int M, int N, int K, int batch,
                  int ksplit, int causal) {
    dim3 g(M / BM, N / BN, batch * ksplit), blk(256);
    if (epi == 3 && !sa && !sb)      gemm_bt<3,0,0><<<g, blk, 0, stream>>>(A,sA,pA,lda,B,sB,pB,ldb,bmod,C,sC,pC,ldc,bias,hmod,M,N,K,ksplit,causal);
    else if (epi == 7)               gemm_bt<7,0,0><<<g, blk, 0, stream>>>(A,sA,pA,lda,B,sB,pB,ldb,bmod,C,sC,pC,ldc,bias,hmod,M,N,K,ksplit,causal);
    else if (epi == 3 && sa && !sb)  gemm_bt<3,1,0><<<g, blk, 0, stream>>>(A,sA,pA,lda,B,sB,pB,ldb,bmod,C,sC,pC,ldc,bias,hmod,M,N,K,ksplit,causal);
    else if (epi == 3)               gemm_bt<3,1,1><<<g, blk, 0, stream>>>(A,sA,pA,lda,B,sB,pB,ldb,bmod,C,sC,pC,ldc,bias,hmod,M,N,K,ksplit,causal);
    else if (epi == 5)               gemm_bt<5,1,1><<<g, blk, 0, stream>>>(A,sA,pA,lda,B,sB,pB,ldb,bmod,C,sC,pC,ldc,bias,hmod,M,N,K,ksplit,causal);
    else if (epi == 6)               gemm_bt<6,1,1><<<g, blk, 0, stream>>>(A,sA,pA,lda,B,sB,pB,ldb,bmod,C,sC,pC,ldc,bias,hmod,M,N,K,ksplit,causal);
  };
  const int BIG = 1 << 30;

  // ---- input projection: h = x @ tin_w^T + tin_b  (split-K x10, atomic) ----
  tinprep_kernel<<<dim3((unsigned)((TIN_H4 + 255) / 256)), dim3(256), 0, stream>>>(
      x, xb, tin_w, Wbig, (float4*)h);
  gemm(3, 0, 0, xb, 0, 0, VOC, Wbig, 0, 0, VOC, BIG, h, 0, 0, DIM, tin_b, 1,
       ROWS, DIM, VOC, 1, 10, 0);

  for (int i = 0; i < DEPTH; ++i) {
    {
      long long tot = 12LL*((long long)DIM*DIM >> 2) + MC_ZR;
      prep_kernel<<<dim3((unsigned)((tot + 255) / 256)), dim3(256), 0, stream>>>(
          wq_w + (size_t)i*DIM*DIM, wk_w + (size_t)i*DIM*DIM, wv_w + (size_t)i*DIM*DIM,
          wo_w + (size_t)i*DIM*DIM, f1_w + (size_t)i*DH*DIM, f2_w + (size_t)i*DIM*DH,
          Wqkv, Wol, Wf1l, Wf2l,
          lc_re + (size_t)i*NH*DQ*DQ, lc_im + (size_t)i*NH*DQ*DQ, vte,
          phz_re + i*NH*DQ, phz_im + i*NH*DQ, theta,
          wq_b + i*DIM, wk_b + i*DIM, wv_b + i*DIM, qkvbi,
          amp + i*NH, dtab, (float4*)ret);
    }

    // retention
    ln_kernel<<<ROWS, 256, 0, stream>>>(h, hb);
    gemm(5, 1, 1, hb, 0, PQKV, DIM, Wqkv, 0, WP, DIM, BIG,
         qkvb, 0, PQKV3, 3*DIM, qkvbi, 1, ROWS, 3*DIM, DIM, 1, 1, 0);
    rotate_kernel<<<dim3(SEQ, NH, BATCH), DQ, 0, stream>>>(
        qkvb, theta, dtab, qrot, krot, SbX);
    vt_kernel<<<dim3(SEQ/64, DQ/64, BATCH*NH), 256, 0, stream>>>(qkvb, vte);
    gemm(7, 0, 0, qrot, (long long)SEQ*2*DQ, 0, 2*DQ,
         krot, (long long)SEQ*2*DQ, 0, 2*DQ, BIG,
         SbX + CROSSK, (long long)SEQ*LDS_X, 0, LDS_X, dtab, NH,
         SEQ, SEQ, 2*DQ, BATCH*NH, 1, 1);
    gemm(3, 0, 0, SbX, (long long)SEQ*LDS_X, 0, LDS_X,
         vte, (long long)DQ*LDS_X, 0, LDS_X, BIG,
         ret, (long long)SEQ*DQ, 0, DQ, nullptr, 1, SEQ, DQ, LDS_X, BATCH*NH, 4, 2);
    siluret_kernel<<<dim3(SEQ, NH, BATCH), DQ, 0, stream>>>(ret, yb);
    gemm(3, 1, 1, yb, 0, PY, DIM, Wol, 0, (long long)DIM*DIM, DIM, BIG,
         h, 0, 0, DIM, wo_b + i*DIM, 1, ROWS, DIM, DIM, 1, 2, 0);

    // FFN
    ln_kernel<<<ROWS, 256, 0, stream>>>(h, hb);
    gemm(6, 1, 1, hb, 0, PQKV, DIM, Wf1l, 0, (long long)DH*DIM, DIM, BIG,
         mid, 0, PMID, DH, f1_b + i*DH, 1, ROWS, DH, DIM, 1, 1, 0);
    gemm(3, 1, 0, mid, 0, PMID, DH, Wf2l, 0, 0, DH, BIG,
         h, 0, 0, DIM, f2_b + i*DIM, 1, ROWS, DIM, DH, 1, 4, 0);
  }

  // ---- output projection: 8-phase 256^2 kernel, 2-pass (Ah*Bh + Al*Bh) ----
  tailprep_kernel<<<dim3((unsigned)((TAIL_W + 255) / 256)), dim3(256), 0, stream>>>(
      h, hb, tout_w, Wbig);
  gemm256<2><<<dim3(ROWS/256, VOC/256, 1), dim3(512), 0, stream>>>(
      hb, PQKV, DIM, Wbig, 0, DIM, (float*)d_out, VOC, tout_b, ROWS, VOC, DIM);
}

// Round 13
// 1737.956 us; speedup vs baseline: 1.0237x; 1.0237x over previous
//
#include <hip/hip_runtime.h>
#include <hip/hip_bf16.h>
#include <stdint.h>

#define DEPTH 4
#define DIM   1024
#define DH    4096
#define NH    8
#define DQ    128
#define VOC   32000
#define BATCH 2
#define SEQ   1024
#define ROWS  (BATCH*SEQ)   // 2048
#define CROSSK 256          // merged cross K-prefix in PV
#define LDS_X (CROSSK + SEQ)  // 1280: row length of SbX / vte

#define PQKV  ((long long)ROWS*DIM)
#define PQKV3 ((long long)ROWS*3*DIM)
#define PROT  ((long long)BATCH*NH*SEQ*2*DQ)
#define PMID  ((long long)ROWS*DH)
#define PY    ((long long)ROWS*DIM)

typedef __hip_bfloat16 bf16;
using f32x4  = __attribute__((ext_vector_type(4))) float;
using bf16x8 = __attribute__((ext_vector_type(8))) __bf16;

__device__ __forceinline__ unsigned short bcu(bf16 h) {
  return __builtin_bit_cast(unsigned short, h);
}

__device__ __forceinline__ void wpair(bf16* p, long long off, long long plane, float v) {
  bf16 hi = __float2bfloat16(v);
  p[off] = hi;
  p[off + plane] = __float2bfloat16(v - __bfloat162float(hi));
}

__device__ __forceinline__ void gload_lds16(const void* g, void* l) {
  __builtin_amdgcn_global_load_lds(
      (const __attribute__((address_space(1))) void*)g,
      (__attribute__((address_space(3))) void*)(uintptr_t)l,
      16, 0, 0);
}

// ---------------------------------------------------------------------------
// Batched GEMM: C[zb] = A[zb] (MxK rm) * B[zb%bmod]^T (NxK rm)
// Tile map: x = m-tiles (fastest -> B-panel L2/L3 reuse), y = n-tiles.
// blockIdx.z = zb*ksplit + kslice (Kc = K/ksplit columns).
// SA/SB: operand has a bf16 lo plane at +pA/+pB; passes = Ah*Bh [+Al*Bh] [+Ah*Bl].
// EPI 0: f32 C = acc+bias              3: f32 C += acc+bias (atomic if ksplit>1)
//     5: pair C = acc+bias             6: pair C = silu(acc+bias)
//     7: bf16 C = acc*decay, decay = dtab[(zb%hmod)*(SEQ+1) + (row-col)] (row>=col)
// causal: 1 = skip blocks fully above diagonal (S; skipped tiles never written)
//         2 = clamp K-loop to kend = tm+BM+CROSSK (merged cross+PV; skip if empty)
// bias added by slice 0 only.
// ---------------------------------------------------------------------------
#define BM 128
#define BN 128
#define BKK 64
#define PL 16384   // one LDS plane: 128 rows x 64 bf16

template<int EPI, int SA, int SB>
__global__ __launch_bounds__(256, (SA || SB) ? 2 : 4)
void gemm_bt(const bf16* __restrict__ A, long long sA, long long pA, int lda,
             const bf16* __restrict__ B, long long sB, long long pB, int ldb, int bmod,
             void* __restrict__ Cv, long long sC, long long pC, int ldc,
             const float* __restrict__ bias, int hmod,
             int M, int N, int K, int ksplit, int causal)
{
  __shared__ int4 sbuf[1024 * (2 + SA + SB)];
  char* Asb = (char*)sbuf;
  char* Bsb = Asb + PL * (1 + SA);

  const int tid  = threadIdx.x;
  const int lane = tid & 63;
  const int wave = tid >> 6;
  const int wr   = wave >> 1;
  const int wc   = wave & 1;
  const int z    = blockIdx.z;
  const int zb   = z / ksplit;
  const int ks   = z - zb * ksplit;
  const int Kc   = K / ksplit;
  const int k0   = ks * Kc;
  const int tm   = blockIdx.x * BM;
  const int tn   = blockIdx.y * BN;

  if (causal == 1 && tn >= tm + BM) return;      // fully-masked S tile
  int kend = k0 + Kc;
  if (causal == 2) {                              // merged cross+PV clamp
    kend = min(kend, tm + BM + CROSSK);
    if (kend <= k0) return;
  }

  const bf16* Ab = A + (long long)zb * sA;
  const bf16* Bb = B + (long long)(zb % bmod) * sB;

  f32x4 acc[4][4] = {};

  for (int kt = k0; kt < kend; kt += BKK) {
#pragma unroll
    for (int j = 0; j < 4; ++j) {
      int slot0 = j*256 + wave*64;          // wave-uniform LDS base
      int i = slot0 + lane;
      int row = i >> 3;
      int gc  = (i & 7) ^ (row & 7);        // inverse-swizzled global chunk
      long long ga = (long long)(tm + row) * lda + kt + gc*8;
      long long gb = (long long)(tn + row) * ldb + kt + gc*8;
      gload_lds16(Ab + ga, Asb + slot0*16);
      if (SA) gload_lds16(Ab + pA + ga, Asb + PL + slot0*16);
      gload_lds16(Bb + gb, Bsb + slot0*16);
      if (SB) gload_lds16(Bb + pB + gb, Bsb + PL + slot0*16);
    }
    __syncthreads();
#pragma unroll
    for (int kh = 0; kh < 2; ++kh) {
      const int cb = kh*4 + (lane >> 4);
      int4 avh[4], bvh[4], avl[4], bvl[4];
#pragma unroll
      for (int mi = 0; mi < 4; ++mi) {
        int m = wr*64 + mi*16 + (lane & 15);
        int off = m*128 + ((cb ^ (m & 7)) << 4);
        avh[mi] = *(const int4*)(Asb + off);
        if (SA) avl[mi] = *(const int4*)(Asb + PL + off);
      }
#pragma unroll
      for (int nj = 0; nj < 4; ++nj) {
        int n = wc*64 + nj*16 + (lane & 15);
        int off = n*128 + ((cb ^ (n & 7)) << 4);
        bvh[nj] = *(const int4*)(Bsb + off);
        if (SB) bvl[nj] = *(const int4*)(Bsb + PL + off);
      }
#pragma unroll
      for (int mi = 0; mi < 4; ++mi)
#pragma unroll
        for (int nj = 0; nj < 4; ++nj)
          acc[mi][nj] = __builtin_amdgcn_mfma_f32_16x16x32_bf16(
              __builtin_bit_cast(bf16x8, avh[mi]),
              __builtin_bit_cast(bf16x8, bvh[nj]), acc[mi][nj], 0, 0, 0);
      if (SA)
#pragma unroll
        for (int mi = 0; mi < 4; ++mi)
#pragma unroll
          for (int nj = 0; nj < 4; ++nj)
            acc[mi][nj] = __builtin_amdgcn_mfma_f32_16x16x32_bf16(
                __builtin_bit_cast(bf16x8, avl[mi]),
                __builtin_bit_cast(bf16x8, bvh[nj]), acc[mi][nj], 0, 0, 0);
      if (SB)
#pragma unroll
        for (int mi = 0; mi < 4; ++mi)
#pragma unroll
          for (int nj = 0; nj < 4; ++nj)
            acc[mi][nj] = __builtin_amdgcn_mfma_f32_16x16x32_bf16(
                __builtin_bit_cast(bf16x8, avh[mi]),
                __builtin_bit_cast(bf16x8, bvl[nj]), acc[mi][nj], 0, 0, 0);
    }
    __syncthreads();
  }

  const float* dtab = (EPI == 7) ? bias + (zb % hmod) * (SEQ + 1) : nullptr;
  const int col = lane & 15;
  const int rb  = (lane >> 4) << 2;
  float* Cf = (float*)Cv + (long long)zb * sC;
  bf16*  Ch = (bf16*) Cv + (long long)zb * sC;

#pragma unroll
  for (int mi = 0; mi < 4; ++mi)
#pragma unroll
    for (int nj = 0; nj < 4; ++nj) {
      long long gn = tn + wc*64 + nj*16 + col;
      float bv_ = (EPI != 7 && bias && ks == 0) ? bias[gn] : 0.f;
#pragma unroll
      for (int r = 0; r < 4; ++r) {
        long long gm = tm + wr*64 + mi*16 + rb + r;
        float v = acc[mi][nj][r] + bv_;
        long long off = gm * (long long)ldc + gn;
        if (EPI == 0)      Cf[off] = v;
        else if (EPI == 3) { if (ksplit > 1) atomicAdd(&Cf[off], v); else Cf[off] += v; }
        else if (EPI == 5) wpair(Ch, off, pC, v);
        else if (EPI == 6) wpair(Ch, off, pC, v / (1.f + __expf(-v)));
        else {
          long long dlt = gm - gn;
          float dcy = (dlt >= 0) ? dtab[dlt] : 0.f;
          Ch[off] = __float2bfloat16(acc[mi][nj][r] * dcy);
        }
      }
    }
}

// ---------------------------------------------------------------------------
// Fused per-layer prep (one launch): float4 weight casts + misc segments.
#define MC_LC (NH*DQ*DQ)
#define MC_TH (MC_LC + NH*DQ)
#define MC_B3 (MC_TH + 3*DIM)
#define MC_DC (MC_B3 + NH*(SEQ+1))
#define MC_ZR (MC_DC + (BATCH*NH*SEQ*DQ)/4)
__global__ void prep_kernel(const float* __restrict__ wq, const float* __restrict__ wk,
                            const float* __restrict__ wv, const float* __restrict__ wo,
                            const float* __restrict__ f1, const float* __restrict__ f2,
                            bf16* __restrict__ Wqkv, bf16* __restrict__ Wol,
                            bf16* __restrict__ Wf1, bf16* __restrict__ Wf2,
                            const float* __restrict__ lcr, const float* __restrict__ lci,
                            bf16* __restrict__ vte,
                            const float* __restrict__ pre, const float* __restrict__ pim,
                            float* __restrict__ theta,
                            const float* __restrict__ bq, const float* __restrict__ bk,
                            const float* __restrict__ bv, float* __restrict__ qkvbi,
                            const float* __restrict__ amp, float* __restrict__ dtab,
                            float4* __restrict__ retz) {
  const long long S1 = (long long)DIM*DIM;
  const long long S4 = S1 >> 2;
  const long long WPq = 3*S1;
  const long long CW4 = 12*S4;
  long long i = (long long)blockIdx.x * blockDim.x + threadIdx.x;
  if (i < CW4) {
    const float* src; bf16 *hi, *lo; long long j4;
    if (i < 3*S4) {
      int t = (int)(i / S4);
      src = (t == 0) ? wq : (t == 1) ? wk : wv;
      j4 = i - (long long)t * S4;
      hi = Wqkv + (long long)t * S1; lo = hi + WPq;
    } else if (i < 4*S4)  { src = wo; j4 = i - 3*S4; hi = Wol; lo = Wol + S1; }
    else if (i < 8*S4)    { src = f1; j4 = i - 4*S4; hi = Wf1; lo = Wf1 + 4*S1; }
    else                  { src = f2; j4 = i - 8*S4; hi = Wf2; lo = nullptr; }
    float4 v = ((const float4*)src)[j4];
    bf16 h0 = __float2bfloat16(v.x), h1 = __float2bfloat16(v.y);
    bf16 h2 = __float2bfloat16(v.z), h3 = __float2bfloat16(v.w);
    ((ushort4*)hi)[j4] = ushort4{bcu(h0), bcu(h1), bcu(h2), bcu(h3)};
    if (lo) {
      bf16 l0 = __float2bfloat16(v.x - __bfloat162float(h0));
      bf16 l1 = __float2bfloat16(v.y - __bfloat162float(h1));
      bf16 l2 = __float2bfloat16(v.z - __bfloat162float(h2));
      bf16 l3 = __float2bfloat16(v.w - __bfloat162float(h3));
      ((ushort4*)lo)[j4] = ushort4{bcu(l0), bcu(l1), bcu(l2), bcu(l3)};
    }
    return;
  }
  long long j = i - CW4;
  if (j < MC_LC) {
    int d = (int)(j & 127), e = (int)((j >> 7) & 127), h = (int)(j >> 14);
    float vr = lcr[((long long)h*DQ + d)*DQ + e];
    float vi = lci[((long long)h*DQ + d)*DQ + e];
    bf16 br = __float2bfloat16(vr), bi = __float2bfloat16(-vi);
#pragma unroll
    for (int b = 0; b < BATCH; ++b) {
      long long base = ((long long)(b*NH + h)*DQ + e) * LDS_X;
      vte[base + d]      = br;
      vte[base + DQ + d] = bi;
    }
  } else if (j < MC_TH) {
    int t = (int)(j - MC_LC);
    theta[t] = atan2f(pim[t], pre[t]);
  } else if (j < MC_B3) {
    int t = (int)(j - MC_TH);
    qkvbi[t] = (t < DIM) ? bq[t] : (t < 2*DIM) ? bk[t - DIM] : bv[t - 2*DIM];
  } else if (j < MC_DC) {
    int t = (int)(j - MC_B3);
    int h = t / (SEQ+1), n = t % (SEQ+1);
    float a = 1.f / (1.f + __expf(-amp[h]));
    dtab[t] = powf(a, (float)n);
  } else if (j < MC_ZR) {
    retz[j - MC_DC] = float4{0.f, 0.f, 0.f, 0.f};
  }
}

#define TIN_X4 ((long long)ROWS*VOC/4)
#define TIN_W4 (TIN_X4 + (long long)DIM*VOC/4)
#define TIN_H4 (TIN_W4 + (long long)ROWS*DIM/4)
__global__ void tinprep_kernel(const float* __restrict__ x, bf16* __restrict__ xb,
                               const float* __restrict__ tw, bf16* __restrict__ twb,
                               float4* __restrict__ hz) {
  long long i = (long long)blockIdx.x * blockDim.x + threadIdx.x;
  const float* src; bf16* dst; long long j;
  if (i < TIN_X4)      { src = x;  dst = xb;  j = i; }
  else if (i < TIN_W4) { src = tw; dst = twb; j = i - TIN_X4; }
  else if (i < TIN_H4) { hz[i - TIN_W4] = float4{0.f,0.f,0.f,0.f}; return; }
  else return;
  float4 v = ((const float4*)src)[j];
  ushort4 o{bcu(__float2bfloat16(v.x)), bcu(__float2bfloat16(v.y)),
            bcu(__float2bfloat16(v.z)), bcu(__float2bfloat16(v.w))};
  ((ushort4*)dst)[j] = o;
}

#define TAIL_H (PQKV)
#define TAIL_W (TAIL_H + (long long)VOC*DIM/4)
__global__ void tailprep_kernel(const float* __restrict__ h, bf16* __restrict__ hb,
                                const float* __restrict__ tw, bf16* __restrict__ twb) {
  long long i = (long long)blockIdx.x * blockDim.x + threadIdx.x;
  if (i < TAIL_H) {
    float v = h[i];
    bf16 hi = __float2bfloat16(v);
    hb[i] = hi;
    hb[i + PQKV] = __float2bfloat16(v - __bfloat162float(hi));
  } else if (i < TAIL_W) {
    long long j = i - TAIL_H;
    float4 v = ((const float4*)tw)[j];
    ushort4 o{bcu(__float2bfloat16(v.x)), bcu(__float2bfloat16(v.y)),
              bcu(__float2bfloat16(v.z)), bcu(__float2bfloat16(v.w))};
    ((ushort4*)twb)[j] = o;
  }
}

__global__ void ln_kernel(const float* __restrict__ in, bf16* __restrict__ out) {
  const int row = blockIdx.x;
  const int tid = threadIdx.x;          // 256
  const float4 v = ((const float4*)(in + (size_t)row*DIM))[tid];
  float s  = v.x + v.y + v.z + v.w;
  float s2 = v.x*v.x + v.y*v.y + v.z*v.z + v.w*v.w;
#pragma unroll
  for (int o = 32; o > 0; o >>= 1) { s += __shfl_xor(s, o); s2 += __shfl_xor(s2, o); }
  __shared__ float red[8];
  const int wv = tid >> 6;
  if ((tid & 63) == 0) { red[wv] = s; red[4 + wv] = s2; }
  __syncthreads();
  s  = red[0] + red[1] + red[2] + red[3];
  s2 = red[4] + red[5] + red[6] + red[7];
  const float mean = s * (1.f / DIM);
  const float var  = s2 * (1.f / DIM) - mean * mean;
  const float inv  = rsqrtf(var + 1e-5f);
  float e0 = (v.x - mean) * inv, e1 = (v.y - mean) * inv;
  float e2 = (v.z - mean) * inv, e3 = (v.w - mean) * inv;
  bf16 h0 = __float2bfloat16(e0), h1 = __float2bfloat16(e1);
  bf16 h2 = __float2bfloat16(e2), h3 = __float2bfloat16(e3);
  bf16 l0 = __float2bfloat16(e0 - __bfloat162float(h0));
  bf16 l1 = __float2bfloat16(e1 - __bfloat162float(h1));
  bf16 l2 = __float2bfloat16(e2 - __bfloat162float(h2));
  bf16 l3 = __float2bfloat16(e3 - __bfloat162float(h3));
  ((ushort4*)(out + (size_t)row*DIM))[tid]        = ushort4{bcu(h0), bcu(h1), bcu(h2), bcu(h3)};
  ((ushort4*)(out + PQKV + (size_t)row*DIM))[tid] = ushort4{bcu(l0), bcu(l1), bcu(l2), bcu(l3)};
}

__global__ void rotate_kernel(const bf16* __restrict__ qkv,
                              const float* __restrict__ theta_t,
                              const float* __restrict__ dtab,
                              bf16* __restrict__ qrot, bf16* __restrict__ krot,
                              bf16* __restrict__ SbX) {
  const int d = threadIdx.x, l = blockIdx.x, h = blockIdx.y, b = blockIdx.z;
  const float theta = theta_t[h*DQ + d];
  const long long rowb = (long long)(b*SEQ + l)*(3*DIM) + h*DQ + d;
  const float qv = __bfloat162float(qkv[rowb]) + __bfloat162float(qkv[rowb + PQKV3]);
  const float kv = __bfloat162float(qkv[rowb + DIM]) + __bfloat162float(qkv[rowb + DIM + PQKV3]);
  float sn, cs;
  sincosf(theta * (float)l, &sn, &cs);
  const long long dst = ((long long)(b*NH + h)*SEQ + l)*(2*DQ) + d;
  qrot[dst]      = __float2bfloat16(qv * cs);
  qrot[dst + DQ] = __float2bfloat16(qv * sn);
  krot[dst]      = __float2bfloat16(kv * cs);
  krot[dst + DQ] = __float2bfloat16(kv * sn);
  float sn2, cs2;
  sincosf(theta * (float)(l + 1), &sn2, &cs2);
  const float ad = dtab[h*(SEQ+1) + l + 1];
  const long long qw = ((long long)(b*NH + h)*SEQ + l)*LDS_X + d;
  SbX[qw]      = __float2bfloat16(qv * ad * cs2);
  SbX[qw + DQ] = __float2bfloat16(qv * ad * sn2);
}

__global__ void vt_kernel(const bf16* __restrict__ qkv, bf16* __restrict__ vte) {
  __shared__ float tile[64][65];
  const int t  = threadIdx.x;           // 256
  const int c  = t & 63, r4 = t >> 6;
  const int m0 = blockIdx.x * 64;
  const int d0 = blockIdx.y * 64;
  const int h  = blockIdx.z & (NH - 1);
  const int b  = blockIdx.z >> 3;
#pragma unroll
  for (int rr = 0; rr < 64; rr += 4) {
    const int m = m0 + rr + r4;
    const long long src = (long long)(b*SEQ + m)*(3*DIM) + 2*DIM + h*DQ + d0 + c;
    tile[rr + r4][c] = __bfloat162float(qkv[src]) + __bfloat162float(qkv[src + PQKV3]);
  }
  __syncthreads();
#pragma unroll
  for (int rr = 0; rr < 64; rr += 4) {
    const int d = rr + r4;
    vte[((long long)(b*NH + h)*DQ + d0 + d)*LDS_X + CROSSK + m0 + c] =
        __float2bfloat16(tile[c][d]);
  }
}

__global__ void siluret_kernel(const float* __restrict__ ret, bf16* __restrict__ y) {
  const int d = threadIdx.x, l = blockIdx.x, h = blockIdx.y, b = blockIdx.z;
  float r = ret[((long long)(b*NH + h)*SEQ + l)*DQ + d];
  float s = r / (1.f + __expf(-r));
  wpair(y, ((long long)(b*SEQ + l)*NH + h)*DQ + d, PY, s);
}

// ---------------------------------------------------------------------------
extern "C" void kernel_launch(void* const* d_in, const int* in_sizes, int n_in,
                              void* d_out, int out_size, void* d_ws, size_t ws_size,
                              hipStream_t stream) {
  const float* x      = (const float*)d_in[0];
  const float* tin_w  = (const float*)d_in[1];
  const float* tin_b  = (const float*)d_in[2];
  const float* tout_w = (const float*)d_in[3];
  const float* tout_b = (const float*)d_in[4];
  const float* wq_w   = (const float*)d_in[5];
  const float* wq_b   = (const float*)d_in[6];
  const float* wk_w   = (const float*)d_in[7];
  const float* wk_b   = (const float*)d_in[8];
  const float* wv_w   = (const float*)d_in[9];
  const float* wv_b   = (const float*)d_in[10];
  const float* wo_w   = (const float*)d_in[11];
  const float* wo_b   = (const float*)d_in[12];
  const float* f1_w   = (const float*)d_in[13];
  const float* f1_b   = (const float*)d_in[14];
  const float* f2_w   = (const float*)d_in[15];
  const float* f2_b   = (const float*)d_in[16];
  const float* phz_re = (const float*)d_in[17];
  const float* phz_im = (const float*)d_in[18];
  const float* amp    = (const float*)d_in[19];
  const float* lc_re  = (const float*)d_in[20];
  const float* lc_im  = (const float*)d_in[21];
  (void)in_sizes; (void)n_in; (void)out_size; (void)ws_size;

  char* w = (char*)d_ws;
  auto alloc = [&](size_t bytes) {
    char* p = w; w += (bytes + 255) & ~(size_t)255; return p;
  };
  auto palloc = [&](long long elems) {       // hi/lo pair, lo at +elems
    return (bf16*)alloc((size_t)elems * 2 * 2);
  };

  const long long WP = 3LL*DIM*DIM;
  float* h     = (float*)alloc((size_t)ROWS*DIM*4);
  float* ret   = (float*)alloc((size_t)BATCH*NH*SEQ*DQ*4);
  float* qkvbi = (float*)alloc((size_t)3*DIM*4);
  float* dtab  = (float*)alloc((size_t)NH*(SEQ+1)*4);
  float* theta = (float*)alloc((size_t)NH*DQ*4);
  bf16*  hb    = palloc(PQKV);
  bf16*  Wqkv  = palloc(WP);
  bf16*  Wol   = palloc((long long)DIM*DIM);
  bf16*  Wf1l  = palloc((long long)DH*DIM);
  bf16*  Wf2l  = (bf16*)alloc((size_t)DIM*DH*2);     // hi only (2-pass f2)
  bf16*  qkvb  = palloc(PQKV3);
  bf16*  Wbig  = (bf16*)alloc((size_t)DIM*VOC*2);    // hi only (tin + 2-pass tout)
  bf16*  qrot  = (bf16*)alloc((size_t)PROT*2);       // single plane
  bf16*  krot  = (bf16*)alloc((size_t)PROT*2);       // single plane
  bf16*  SbX   = (bf16*)alloc((size_t)BATCH*NH*SEQ*LDS_X*2);  // [qwb | S]
  bf16*  vte   = (bf16*)alloc((size_t)BATCH*NH*DQ*LDS_X*2);   // [lcc | V^T]
  bf16*  mid   = palloc(PMID);
  // aliases (lifetimes disjoint):
  bf16*  xb = (bf16*)d_out;    // bf16 x in d_out; dead before tout writes
  bf16*  yb = qkvb;            // silu(ret) pair; qkvb dead after rotate/vt

  auto gemm = [&](int epi, int sa, int sb, const bf16* A, long long sA, long long pA, int lda,
                  const bf16* B, long long sB, long long pB, int ldb, int bmod,
                  void* C, long long sC, long long pC, int ldc,
                  const float* bias, int hmod, int M, int N, int K, int batch,
                  int ksplit, int causal) {
    dim3 g(M / BM, N / BN, batch * ksplit), blk(256);
    if (epi == 3 && !sa && !sb)      gemm_bt<3,0,0><<<g, blk, 0, stream>>>(A,sA,pA,lda,B,sB,pB,ldb,bmod,C,sC,pC,ldc,bias,hmod,M,N,K,ksplit,causal);
    else if (epi == 7)               gemm_bt<7,0,0><<<g, blk, 0, stream>>>(A,sA,pA,lda,B,sB,pB,ldb,bmod,C,sC,pC,ldc,bias,hmod,M,N,K,ksplit,causal);
    else if (epi == 0 && sa && !sb)  gemm_bt<0,1,0><<<g, blk, 0, stream>>>(A,sA,pA,lda,B,sB,pB,ldb,bmod,C,sC,pC,ldc,bias,hmod,M,N,K,ksplit,causal);
    else if (epi == 3 && sa && !sb)  gemm_bt<3,1,0><<<g, blk, 0, stream>>>(A,sA,pA,lda,B,sB,pB,ldb,bmod,C,sC,pC,ldc,bias,hmod,M,N,K,ksplit,causal);
    else if (epi == 3)               gemm_bt<3,1,1><<<g, blk, 0, stream>>>(A,sA,pA,lda,B,sB,pB,ldb,bmod,C,sC,pC,ldc,bias,hmod,M,N,K,ksplit,causal);
    else if (epi == 5)               gemm_bt<5,1,1><<<g, blk, 0, stream>>>(A,sA,pA,lda,B,sB,pB,ldb,bmod,C,sC,pC,ldc,bias,hmod,M,N,K,ksplit,causal);
    else if (epi == 6)               gemm_bt<6,1,1><<<g, blk, 0, stream>>>(A,sA,pA,lda,B,sB,pB,ldb,bmod,C,sC,pC,ldc,bias,hmod,M,N,K,ksplit,causal);
  };
  const int BIG = 1 << 30;

  // ---- input projection: h = x @ tin_w^T + tin_b  (split-K x10, atomic) ----
  tinprep_kernel<<<dim3((unsigned)((TIN_H4 + 255) / 256)), dim3(256), 0, stream>>>(
      x, xb, tin_w, Wbig, (float4*)h);
  gemm(3, 0, 0, xb, 0, 0, VOC, Wbig, 0, 0, VOC, BIG, h, 0, 0, DIM, tin_b, 1,
       ROWS, DIM, VOC, 1, 10, 0);

  for (int i = 0; i < DEPTH; ++i) {
    {
      long long tot = 12LL*((long long)DIM*DIM >> 2) + MC_ZR;
      prep_kernel<<<dim3((unsigned)((tot + 255) / 256)), dim3(256), 0, stream>>>(
          wq_w + (size_t)i*DIM*DIM, wk_w + (size_t)i*DIM*DIM, wv_w + (size_t)i*DIM*DIM,
          wo_w + (size_t)i*DIM*DIM, f1_w + (size_t)i*DH*DIM, f2_w + (size_t)i*DIM*DH,
          Wqkv, Wol, Wf1l, Wf2l,
          lc_re + (size_t)i*NH*DQ*DQ, lc_im + (size_t)i*NH*DQ*DQ, vte,
          phz_re + i*NH*DQ, phz_im + i*NH*DQ, theta,
          wq_b + i*DIM, wk_b + i*DIM, wv_b + i*DIM, qkvbi,
          amp + i*NH, dtab, (float4*)ret);
    }

    // retention
    ln_kernel<<<ROWS, 256, 0, stream>>>(h, hb);
    gemm(5, 1, 1, hb, 0, PQKV, DIM, Wqkv, 0, WP, DIM, BIG,
         qkvb, 0, PQKV3, 3*DIM, qkvbi, 1, ROWS, 3*DIM, DIM, 1, 1, 0);
    rotate_kernel<<<dim3(SEQ, NH, BATCH), DQ, 0, stream>>>(
        qkvb, theta, dtab, qrot, krot, SbX);
    vt_kernel<<<dim3(SEQ/64, DQ/64, BATCH*NH), 256, 0, stream>>>(qkvb, vte);
    gemm(7, 0, 0, qrot, (long long)SEQ*2*DQ, 0, 2*DQ,
         krot, (long long)SEQ*2*DQ, 0, 2*DQ, BIG,
         SbX + CROSSK, (long long)SEQ*LDS_X, 0, LDS_X, dtab, NH,
         SEQ, SEQ, 2*DQ, BATCH*NH, 1, 1);
    gemm(3, 0, 0, SbX, (long long)SEQ*LDS_X, 0, LDS_X,
         vte, (long long)DQ*LDS_X, 0, LDS_X, BIG,
         ret, (long long)SEQ*DQ, 0, DQ, nullptr, 1, SEQ, DQ, LDS_X, BATCH*NH, 4, 2);
    siluret_kernel<<<dim3(SEQ, NH, BATCH), DQ, 0, stream>>>(ret, yb);
    gemm(3, 1, 1, yb, 0, PY, DIM, Wol, 0, (long long)DIM*DIM, DIM, BIG,
         h, 0, 0, DIM, wo_b + i*DIM, 1, ROWS, DIM, DIM, 1, 2, 0);

    // FFN
    ln_kernel<<<ROWS, 256, 0, stream>>>(h, hb);
    gemm(6, 1, 1, hb, 0, PQKV, DIM, Wf1l, 0, (long long)DH*DIM, DIM, BIG,
         mid, 0, PMID, DH, f1_b + i*DH, 1, ROWS, DH, DIM, 1, 1, 0);
    gemm(3, 1, 0, mid, 0, PMID, DH, Wf2l, 0, 0, DH, BIG,
         h, 0, 0, DIM, f2_b + i*DIM, 1, ROWS, DIM, DH, 1, 4, 0);
  }

  // ---- output projection: 2-pass (A=hb pair, B=tout_w hi only) ----
  tailprep_kernel<<<dim3((unsigned)((TAIL_W + 255) / 256)), dim3(256), 0, stream>>>(
      h, hb, tout_w, Wbig);
  gemm(0, 1, 0, hb, 0, PQKV, DIM, Wbig, 0, 0, DIM, BIG,
       (float*)d_out, 0, 0, VOC, tout_b, 1, ROWS, VOC, DIM, 1, 1, 0);
}